// Round 3
// baseline (474.697 us; speedup 1.0000x reference)
//
#include <hip/hip_runtime.h>
#include <math.h>

// Heatmap peak detection: 3x3 max-pool (stride 1, -inf pad) == identity mask,
// gated by sigmoid(x) > 0.05. Input [16,17,512,512] f32 -> 272 planes of 512x512.
#define HM_W 512
#define HM_H 512
#define TILE_ROWS 16                 // output rows per block (halo amp = 18/16 = 1.125x)
#define HALO_ROWS (TILE_ROWS + 2)
#define LDS_STRIDE 516               // 512 + 4 floats pad (16B-aligned stride)
#define SIG_THRESH 0.05f

// native clang vector type: required by __builtin_nontemporal_store
typedef float f32x4 __attribute__((ext_vector_type(4)));

__global__ __launch_bounds__(512) void heatmap_peak_kernel(
    const float* __restrict__ in, float* __restrict__ out) {
    // 18 rows x 512 cols staged; 37.2 KB LDS -> up to 4 blocks/CU.
    __shared__ float s[HALO_ROWS][LDS_STRIDE];

    const int tx = threadIdx.x;             // 0..127  (float4 column)
    const int ty = threadIdx.y;             // 0..3
    const int t  = ty * 128 + tx;           // flat 0..511
    const int y0 = blockIdx.y * TILE_ROWS;  // first output row of tile
    const long long base = (long long)blockIdx.z * (HM_H * HM_W);

    // ---- Stage 18 rows: 18*128 = 2304 float4 loads over 512 threads ----
    for (int i = t; i < HALO_ROWS * 128; i += 512) {
        const int r  = i >> 7;        // LDS row 0..17
        const int c  = i & 127;       // vec4 col
        const int gy = y0 - 1 + r;    // global row (halo: -1 .. y0+16)
        float4 v;
        if (gy >= 0 && gy < HM_H) {
            v = ((const float4*)(in + base + (long long)gy * HM_W))[c];
        } else {
            v = make_float4(-INFINITY, -INFINITY, -INFINITY, -INFINITY);
        }
        *(float4*)&s[r][c * 4] = v;
    }
    __syncthreads();

    const int x0   = tx * 4;
    const int row0 = ty * 4;   // this thread covers output rows row0..row0+3 (LDS-relative)
    const bool has_l = (x0 != 0);
    const bool has_r = (x0 + 4 < HM_W);

    // Rolling 3-row window: a = top, b = center, c4 = bottom. Init with rows row0, row0+1.
    float4 a = *(const float4*)&s[row0][x0];
    float4 b = *(const float4*)&s[row0 + 1][x0];
    float la = has_l ? s[row0][x0 - 1]     : -INFINITY;
    float lb = has_l ? s[row0 + 1][x0 - 1] : -INFINITY;
    float ra = has_r ? s[row0][x0 + 4]     : -INFINITY;
    float rb = has_r ? s[row0 + 1][x0 + 4] : -INFINITY;

    #pragma unroll
    for (int k = 0; k < 4; ++k) {
        const int rr = row0 + k;               // window top LDS row; center = rr+1
        const float4 c4 = *(const float4*)&s[rr + 2][x0];
        const float  lc = has_l ? s[rr + 2][x0 - 1] : -INFINITY;
        const float  rc = has_r ? s[rr + 2][x0 + 4] : -INFINITY;

        // vertical max over 3 rows
        float4 vm;
        vm.x = fmaxf(fmaxf(a.x, b.x), c4.x);
        vm.y = fmaxf(fmaxf(a.y, b.y), c4.y);
        vm.z = fmaxf(fmaxf(a.z, b.z), c4.z);
        vm.w = fmaxf(fmaxf(a.w, b.w), c4.w);
        const float lm = fmaxf(fmaxf(la, lb), lc);
        const float rm = fmaxf(fmaxf(ra, rb), rc);

        // horizontal max over 3 columns
        float4 hm;
        hm.x = fmaxf(lm,   fmaxf(vm.x, vm.y));
        hm.y = fmaxf(vm.x, fmaxf(vm.y, vm.z));
        hm.z = fmaxf(vm.y, fmaxf(vm.z, vm.w));
        hm.w = fmaxf(vm.z, fmaxf(vm.w, rm));

        // peak mask + sigmoid score (center row = b)
        f32x4 o;
        {
            const float sc = 1.0f / (1.0f + __expf(-b.x));
            o.x = (hm.x == b.x && sc > SIG_THRESH) ? sc : 0.0f;
        }
        {
            const float sc = 1.0f / (1.0f + __expf(-b.y));
            o.y = (hm.y == b.y && sc > SIG_THRESH) ? sc : 0.0f;
        }
        {
            const float sc = 1.0f / (1.0f + __expf(-b.z));
            o.z = (hm.z == b.z && sc > SIG_THRESH) ? sc : 0.0f;
        }
        {
            const float sc = 1.0f / (1.0f + __expf(-b.w));
            o.w = (hm.w == b.w && sc > SIG_THRESH) ? sc : 0.0f;
        }

        // write-once output: non-temporal so it doesn't evict input halos from L2
        f32x4* optr = (f32x4*)(out + base + (long long)(y0 + rr) * HM_W) + tx;
        __builtin_nontemporal_store(o, optr);

        // roll the window down one row
        a = b; b = c4;
        la = lb; lb = lc;
        ra = rb; rb = rc;
    }
}

extern "C" void kernel_launch(void* const* d_in, const int* in_sizes, int n_in,
                              void* d_out, int out_size, void* d_ws, size_t ws_size,
                              hipStream_t stream) {
    const float* heatmaps = (const float*)d_in[0];
    float* out = (float*)d_out;

    const int planes = in_sizes[0] / (HM_H * HM_W);  // B*num_kps = 272

    dim3 block(128, 4, 1);
    dim3 grid(1, HM_H / TILE_ROWS, planes);
    heatmap_peak_kernel<<<grid, block, 0, stream>>>(heatmaps, out);
}